// Round 10
// baseline (526.212 us; speedup 1.0000x reference)
//
#include <hip/hip_runtime.h>
#include <math.h>

#define PW 32
#define PL 64
#define PK 512
#define PN 64
// vectors total: PW*PL*PK = 1,048,576

typedef int   v4i __attribute__((ext_vector_type(4)));
typedef float v4f __attribute__((ext_vector_type(4)));

// Permuted bit order (used by pack, Afrag build, B-extract, epilogue):
//   state element i = 4e + c  <->  mask bit position p = c*16 + e.
// This makes 4 per-component ballots over a float4 load produce the packed
// mask directly (no cross-lane transpose), and A/B use the same k-order so
// the MFMA dot products are unchanged (all-integer => bit-exact vs round 9).

// ---------------- Kernel 0: pack states -> 64-bit masks ----------------
// Wave handles 16 vectors: 4 iters x (1 float4 load = 4 vectors, 4 ballots,
// scalar mask assembly). Pure-BW: 268 MB read + 8 MB write.
__global__ __launch_bounds__(256) void pack_kernel(
    const float* __restrict__ states, unsigned long long* __restrict__ pmask)
{
    const int lane = threadIdx.x & 63;
    const long wave = ((long)blockIdx.x * blockDim.x + threadIdx.x) >> 6;
    const long vb = wave * 16;                    // first vector of this wave

    unsigned long long pm = 0;
#pragma unroll
    for (int it = 0; it < 4; ++it) {
        const v4f* gp = (const v4f*)(states + (vb + it * 4) * PN);
        const v4f f = gp[lane];                   // 1 KiB coalesced
        const unsigned long long m0 = __ballot(f.x != 0.0f);
        const unsigned long long m1 = __ballot(f.y != 0.0f);
        const unsigned long long m2 = __ballot(f.z != 0.0f);
        const unsigned long long m3 = __ballot(f.w != 0.0f);
        unsigned long long mm[4];
#pragma unroll
        for (int vv = 0; vv < 4; ++vv) {
            mm[vv] = ((m0 >> (vv * 16)) & 0xFFFFull)
                   | (((m1 >> (vv * 16)) & 0xFFFFull) << 16)
                   | (((m2 >> (vv * 16)) & 0xFFFFull) << 32)
                   | (((m3 >> (vv * 16)) & 0xFFFFull) << 48);
        }
        const unsigned long long s01 = (lane & 1) ? mm[1] : mm[0];
        const unsigned long long s23 = (lane & 1) ? mm[3] : mm[2];
        const unsigned long long sel = (lane & 2) ? s23 : s01;
        pm = ((lane >> 2) == it) ? sel : pm;
    }
    if (lane < 16) pmask[vb + lane] = pm;         // 128 B coalesced
}

// ---------------- Kernel 1: energies via exact-int i8 MFMA ----------------
// R = llrint(Q * 2^28), 4 signed base-256 i8 digits; i32 MFMA exact; digits
// recombined in int64, scaled 2^-28 (e64 bit-identical to round 9).
// Layouts: A[m][p]: m=lane&15 (=j_local), p=(lane>>4)*16+b; element i(p)=4b+h.
//          B[p][v]: v=lane&15; byte b at group h is bit (h*16+b) of pm[v].
//          C[m][v]: v=lane&15, m=(lane>>4)*4+reg.
// Epilogue: s_j for j=jt*16+h*4+r is bit (r*16+jt*4+h) of pm[v].
constexpr int ITERS_PER_WAVE = 4;   // 32 vectors/iter -> 128 vectors/wave

__global__ __launch_bounds__(256) void energies_kernel(
    const unsigned long long* __restrict__ pmask, const float* __restrict__ Q,
    float* __restrict__ e_out, double* __restrict__ e64)
{
    __shared__ alignas(16) signed char Afrag[16 * 64 * 16];  // [k*4+jt][lane][b]

    const int tid  = threadIdx.x;
    const int lane = tid & 63;
    const int wv   = tid >> 6;
    const int w    = blockIdx.x >> 6;        // 64 blocks per w
    const int blk  = blockIdx.x & 63;

    // ---- build permuted digit fragments of Q[w] in LDS ----
    const float* Qw = Q + w * PN * PN;
    for (int e = tid; e < PN * PN; e += 256) {
        const int i = e >> 6, j = e & 63;
        long long R = llrint((double)Qw[e] * 268435456.0);   // * 2^28
        const int h = i & 3, b = i >> 2;                     // permuted k-pos
        const int frag_lane = (h << 4) | (j & 15);
        const int jt = j >> 4;
#pragma unroll
        for (int k = 0; k < 4; ++k) {
            const signed char d = (signed char)(R & 0xFF);
            R = (R - d) >> 8;
            Afrag[((k * 4 + jt) * 64 + frag_lane) * 16 + b] = d;
        }
    }
    __syncthreads();

    const v4i* Af = (const v4i*)Afrag;       // [(k*4+jt)*64 + lane]

    const long vw_base = (long)w * (PL * PK)
                       + (long)(blk * 4 + wv) * (32 * ITERS_PER_WAVE);
    const int h = lane >> 4;

    for (int t = 0; t < ITERS_PER_WAVE; ++t) {
        const long vbase = vw_base + (long)t * 32;

        // ---- per-lane packed masks of vectors (lane&15) and (+16) ----
        const unsigned long long pmA = pmask[vbase + (lane & 15)];
        const unsigned long long pmB = pmask[vbase + 16 + (lane & 15)];

        // ---- B fragments: byte b at group h = bit (h*16+b) of pm ----
        const unsigned int bA = (unsigned int)(pmA >> (h * 16)) & 0xFFFFu;
        const unsigned int bB = (unsigned int)(pmB >> (h * 16)) & 0xFFFFu;
        v4i BA, BB;
#pragma unroll
        for (int q = 0; q < 4; ++q) {
            BA[q] = (int)((((bA >> (4 * q)) & 0xFu) * 0x00204081u) & 0x01010101u);
            BB[q] = (int)((((bB >> (4 * q)) & 0xFu) * 0x01010101u >> 0) & 0x01010101u);
        }
        // (fix BB expansion to match BA's magic)
#pragma unroll
        for (int q = 0; q < 4; ++q)
            BB[q] = (int)((((bB >> (4 * q)) & 0xFu) * 0x00204081u) & 0x01010101u);

        // ---- epilogue select bits: for row r, nibble over jt ----
        unsigned int xA[4], xB[4];
#pragma unroll
        for (int r = 0; r < 4; ++r) {
            xA[r] = (unsigned int)(pmA >> (r * 16 + h)) & 0x1111u;
            xB[r] = (unsigned int)(pmB >> (r * 16 + h)) & 0x1111u;
        }

        long long accA = 0, accB = 0;
#pragma unroll
        for (int k = 0; k < 4; ++k) {
            v4i A0 = Af[(k * 4 + 0) * 64 + lane];
            v4i A1 = Af[(k * 4 + 1) * 64 + lane];
            v4i A2 = Af[(k * 4 + 2) * 64 + lane];
            v4i A3 = Af[(k * 4 + 3) * 64 + lane];
            v4i CA0 = {0,0,0,0}, CA1 = {0,0,0,0}, CA2 = {0,0,0,0}, CA3 = {0,0,0,0};
            v4i CB0 = {0,0,0,0}, CB1 = {0,0,0,0}, CB2 = {0,0,0,0}, CB3 = {0,0,0,0};
            asm("s_nop 1\n\t"
                "v_mfma_i32_16x16x64_i8 %0, %8, %12, %0\n\t"
                "v_mfma_i32_16x16x64_i8 %4, %8, %13, %4\n\t"
                "v_mfma_i32_16x16x64_i8 %1, %9, %12, %1\n\t"
                "v_mfma_i32_16x16x64_i8 %5, %9, %13, %5\n\t"
                "v_mfma_i32_16x16x64_i8 %2, %10, %12, %2\n\t"
                "v_mfma_i32_16x16x64_i8 %6, %10, %13, %6\n\t"
                "v_mfma_i32_16x16x64_i8 %3, %11, %12, %3\n\t"
                "v_mfma_i32_16x16x64_i8 %7, %11, %13, %7\n\t"
                "s_nop 7\n\t"
                "s_nop 7"
                : "+v"(CA0), "+v"(CA1), "+v"(CA2), "+v"(CA3),
                  "+v"(CB0), "+v"(CB1), "+v"(CB2), "+v"(CB3)
                : "v"(A0), "v"(A1), "v"(A2), "v"(A3), "v"(BA), "v"(BB));
            int akA = 0, akB = 0;
#pragma unroll
            for (int r = 0; r < 4; ++r) {
                akA += ((xA[r] >> 0)  & 1) * CA0[r];
                akA += ((xA[r] >> 4)  & 1) * CA1[r];
                akA += ((xA[r] >> 8)  & 1) * CA2[r];
                akA += ((xA[r] >> 12) & 1) * CA3[r];
                akB += ((xB[r] >> 0)  & 1) * CB0[r];
                akB += ((xB[r] >> 4)  & 1) * CB1[r];
                akB += ((xB[r] >> 8)  & 1) * CB2[r];
                akB += ((xB[r] >> 12) & 1) * CB3[r];
            }
            accA += (long long)akA << (8 * k);
            accB += (long long)akB << (8 * k);
        }

        // ---- reduce the 4 lane-groups holding the same v = lane&15 ----
        accA += __shfl_xor(accA, 16, 64);
        accA += __shfl_xor(accA, 32, 64);
        accB += __shfl_xor(accB, 16, 64);
        accB += __shfl_xor(accB, 32, 64);

        if (lane < 16) {
            const double eA = (double)accA * 0x1p-28;
            const double eB = (double)accB * 0x1p-28;
            e64[vbase + lane]        = eA;
            e_out[vbase + lane]      = (float)eA;
            e64[vbase + 16 + lane]   = eB;
            e_out[vbase + 16 + lane] = (float)eB;
        }
    }
}

// ---------------- Kernel 2: exchange masks ----------------
__global__ __launch_bounds__(256) void mask_kernel(
    const double* __restrict__ e64, const float* __restrict__ beta,
    const float* __restrict__ u, unsigned char* __restrict__ mask)
{
    const int idx = blockIdx.x * blockDim.x + threadIdx.x;
    if (idx >= PW * (PL - 1) * PK) return;
    const int k = idx % PK;
    const int m = (idx / PK) % (PL - 1);
    const int w = idx / (PK * (PL - 1));
    const long e1 = ((long)w * PL + m) * PK + k;
    const double db = (double)beta[m + 1] - (double)beta[m];
    const double delta = (e64[e1 + PK] - e64[e1]) * db;
    mask[idx] = ((double)u[idx] < exp(delta)) ? 1 : 0;
}

// ---------------- Kernel 3: masked replica swap (round-7 exact) ----------
// new[w,0]   = mask[w,0]   ? s[w,1]   : s[w,0]
// new[w,l>0] = mask[w,l-1] ? s[w,l-1] : s[w,l]
__global__ __launch_bounds__(256) void swap_kernel(
    const float* __restrict__ states, const unsigned char* __restrict__ mask,
    float* __restrict__ out)
{
    const long rowBase = (long)blockIdx.x * 32;     // (w*L + l)*K + k0
    const int w  = (int)(rowBase >> 15);            // / (L*K)
    const int l  = (int)((rowBase >> 9) & 63);
    const int k0 = (int)(rowBase & 511);

    const int tid = threadIdx.x;
    const int r  = tid >> 3;                        // row within block, 0..31
    const int j4 = tid & 7;                         // float4 index 0..7 (x2)
    const int k  = k0 + r;

    const int ml = (l == 0) ? 0 : (l - 1);
    const unsigned char mk = mask[((long)w * (PL - 1) + ml) * PK + k];
    int sl;
    if (l == 0) sl = mk ? 1 : 0;
    else        sl = mk ? (l - 1) : l;

    const float4* srcp = (const float4*)(states + (((long)w * PL + sl) * PK + k) * PN);
    float4*       dstp = (float4*)(out + (rowBase + r) * PN);
    dstp[j4]     = srcp[j4];
    dstp[j4 + 8] = srcp[j4 + 8];
}

extern "C" void kernel_launch(void* const* d_in, const int* in_sizes, int n_in,
                              void* d_out, int out_size, void* d_ws, size_t ws_size,
                              hipStream_t stream) {
    const float* states = (const float*)d_in[0];
    const float* Q      = (const float*)d_in[1];
    const float* beta   = (const float*)d_in[2];
    const float* u      = (const float*)d_in[3];

    float* e_out      = (float*)d_out;
    float* new_states = (float*)d_out + (long)PW * PL * PK;

    const long NV = (long)PW * PL * PK;
    double* e64 = (double*)d_ws;                               // 8 MB
    unsigned long long* pmask = (unsigned long long*)((char*)d_ws + 8 * NV); // 8 MB
    unsigned char* mask = (unsigned char*)d_ws + 16 * NV;      // 1 MB

    // K0: 1M vectors / 16 per wave / 4 waves = 16384 blocks
    pack_kernel<<<16384, 256, 0, stream>>>(states, pmask);

    // K1: 2048 blocks; block = 4 waves; wave = 4 iters x 32 vectors
    energies_kernel<<<2048, 256, 0, stream>>>(pmask, Q, e_out, e64);

    const int nmask = PW * (PL - 1) * PK;
    mask_kernel<<<(nmask + 255) / 256, 256, 0, stream>>>(e64, beta, u, mask);

    // K3: 1,048,576 rows / 32 per block = 32768 blocks
    swap_kernel<<<32768, 256, 0, stream>>>(states, mask, new_states);
}

// Round 11
// 513.498 us; speedup vs baseline: 1.0248x; 1.0248x over previous
//
#include <hip/hip_runtime.h>
#include <math.h>

#define PW 32
#define PL 64
#define PK 512
#define PN 64
// vectors total: PW*PL*PK = 1,048,576

typedef int   v4i __attribute__((ext_vector_type(4)));
typedef float v4f __attribute__((ext_vector_type(4)));

// Permuted bit order everywhere: state element i = 4e + c  <->  bit p = c*16 + e.
// (4 per-component ballots over a float4 load give the packed mask directly;
// A-fragments use the same k-order so MFMA dot products are unchanged.)

// ---------------- Kernel 1: pack + energies (exact-int i8 MFMA) ----------
// R = llrint(Q * 2^28), 4 signed base-256 i8 digits; i32 MFMA exact; digits
// recombined in int64, scaled 2^-28 (e64 bit-identical to rounds 9/10).
// Also emits pmask (64-bit occupancy per vector) for the expand-swap kernel.
constexpr int ITERS_PER_WAVE = 4;   // 32 vectors/iter -> 128 vectors/wave

__global__ __launch_bounds__(256) void energies_kernel(
    const float* __restrict__ states, const float* __restrict__ Q,
    float* __restrict__ e_out, double* __restrict__ e64,
    unsigned long long* __restrict__ pmask)
{
    __shared__ alignas(16) signed char Afrag[16 * 64 * 16];  // [k*4+jt][lane][b]

    const int tid  = threadIdx.x;
    const int lane = tid & 63;
    const int wv   = tid >> 6;
    const int w    = blockIdx.x >> 6;        // 64 blocks per w
    const int blk  = blockIdx.x & 63;

    // ---- build permuted digit fragments of Q[w] in LDS ----
    const float* Qw = Q + w * PN * PN;
    for (int e = tid; e < PN * PN; e += 256) {
        const int i = e >> 6, j = e & 63;
        long long R = llrint((double)Qw[e] * 268435456.0);   // * 2^28
        const int h = i & 3, b = i >> 2;                     // permuted k-pos
        const int frag_lane = (h << 4) | (j & 15);
        const int jt = j >> 4;
#pragma unroll
        for (int k = 0; k < 4; ++k) {
            const signed char d = (signed char)(R & 0xFF);
            R = (R - d) >> 8;
            Afrag[((k * 4 + jt) * 64 + frag_lane) * 16 + b] = d;
        }
    }
    __syncthreads();

    const v4i* Af = (const v4i*)Afrag;       // [(k*4+jt)*64 + lane]

    const long vw_base = (long)w * (PL * PK)
                       + (long)(blk * 4 + wv) * (32 * ITERS_PER_WAVE);
    const int h   = lane >> 4;
    const int g16 = (lane & 3) * 16;         // this lane's ballot slice
    const int itA = (lane & 15) >> 2;        // iter holding vector lane&15
    const int itO = (lane & 31) >> 2;        // iter holding vector lane&31

    for (int t = 0; t < ITERS_PER_WAVE; ++t) {
        const long vbase = vw_base + (long)t * 32;

        // ---- pack 32 vectors: 8 x (1 KiB float4 load + 4 ballots) ----
        // Vector v = it*4+g occupies slice g of the 4 ballots; every lane
        // builds the candidate for g = lane&3 and keeps it when `it` matches.
        unsigned long long pmA = 0, pmB = 0, pmO = 0;
#pragma unroll
        for (int it = 0; it < 8; ++it) {
            const v4f f = ((const v4f*)(states + (vbase + it * 4) * PN))[lane];
            const unsigned long long m0 = __ballot(f.x != 0.0f);
            const unsigned long long m1 = __ballot(f.y != 0.0f);
            const unsigned long long m2 = __ballot(f.z != 0.0f);
            const unsigned long long m3 = __ballot(f.w != 0.0f);
            const unsigned long long cand =
                  ((m0 >> g16) & 0xFFFFull)
                | (((m1 >> g16) & 0xFFFFull) << 16)
                | (((m2 >> g16) & 0xFFFFull) << 32)
                | (((m3 >> g16) & 0xFFFFull) << 48);
            pmA = (it == itA)     ? cand : pmA;   // vector lane&15
            pmB = (it == itA + 4) ? cand : pmB;   // vector 16+(lane&15)
            pmO = (it == itO)     ? cand : pmO;   // vector lane&31 (owner)
        }
        if (lane < 32) pmask[vbase + lane] = pmO;

        // ---- B fragments: byte b at group h = bit (h*16+b) of pm ----
        const unsigned int bA = (unsigned int)(pmA >> (h * 16)) & 0xFFFFu;
        const unsigned int bB = (unsigned int)(pmB >> (h * 16)) & 0xFFFFu;
        v4i BA, BB;
#pragma unroll
        for (int q = 0; q < 4; ++q) {
            BA[q] = (int)((((bA >> (4 * q)) & 0xFu) * 0x00204081u) & 0x01010101u);
            BB[q] = (int)((((bB >> (4 * q)) & 0xFu) * 0x00204081u) & 0x01010101u);
        }

        // ---- epilogue select bits: for row r, nibble over jt ----
        unsigned int xA[4], xB[4];
#pragma unroll
        for (int r = 0; r < 4; ++r) {
            xA[r] = (unsigned int)(pmA >> (r * 16 + h)) & 0x1111u;
            xB[r] = (unsigned int)(pmB >> (r * 16 + h)) & 0x1111u;
        }

        long long accA = 0, accB = 0;
#pragma unroll
        for (int k = 0; k < 4; ++k) {
            v4i A0 = Af[(k * 4 + 0) * 64 + lane];
            v4i A1 = Af[(k * 4 + 1) * 64 + lane];
            v4i A2 = Af[(k * 4 + 2) * 64 + lane];
            v4i A3 = Af[(k * 4 + 3) * 64 + lane];
            v4i CA0 = {0,0,0,0}, CA1 = {0,0,0,0}, CA2 = {0,0,0,0}, CA3 = {0,0,0,0};
            v4i CB0 = {0,0,0,0}, CB1 = {0,0,0,0}, CB2 = {0,0,0,0}, CB3 = {0,0,0,0};
            asm("s_nop 1\n\t"
                "v_mfma_i32_16x16x64_i8 %0, %8, %12, %0\n\t"
                "v_mfma_i32_16x16x64_i8 %4, %8, %13, %4\n\t"
                "v_mfma_i32_16x16x64_i8 %1, %9, %12, %1\n\t"
                "v_mfma_i32_16x16x64_i8 %5, %9, %13, %5\n\t"
                "v_mfma_i32_16x16x64_i8 %2, %10, %12, %2\n\t"
                "v_mfma_i32_16x16x64_i8 %6, %10, %13, %6\n\t"
                "v_mfma_i32_16x16x64_i8 %3, %11, %12, %3\n\t"
                "v_mfma_i32_16x16x64_i8 %7, %11, %13, %7\n\t"
                "s_nop 7\n\t"
                "s_nop 7"
                : "+v"(CA0), "+v"(CA1), "+v"(CA2), "+v"(CA3),
                  "+v"(CB0), "+v"(CB1), "+v"(CB2), "+v"(CB3)
                : "v"(A0), "v"(A1), "v"(A2), "v"(A3), "v"(BA), "v"(BB));
            int akA = 0, akB = 0;
#pragma unroll
            for (int r = 0; r < 4; ++r) {
                akA += ((xA[r] >> 0)  & 1) * CA0[r];
                akA += ((xA[r] >> 4)  & 1) * CA1[r];
                akA += ((xA[r] >> 8)  & 1) * CA2[r];
                akA += ((xA[r] >> 12) & 1) * CA3[r];
                akB += ((xB[r] >> 0)  & 1) * CB0[r];
                akB += ((xB[r] >> 4)  & 1) * CB1[r];
                akB += ((xB[r] >> 8)  & 1) * CB2[r];
                akB += ((xB[r] >> 12) & 1) * CB3[r];
            }
            accA += (long long)akA << (8 * k);
            accB += (long long)akB << (8 * k);
        }

        // ---- reduce the 4 lane-groups holding the same v = lane&15 ----
        accA += __shfl_xor(accA, 16, 64);
        accA += __shfl_xor(accA, 32, 64);
        accB += __shfl_xor(accB, 16, 64);
        accB += __shfl_xor(accB, 32, 64);

        if (lane < 16) {
            const double eA = (double)accA * 0x1p-28;
            const double eB = (double)accB * 0x1p-28;
            e64[vbase + lane]        = eA;
            e_out[vbase + lane]      = (float)eA;
            e64[vbase + 16 + lane]   = eB;
            e_out[vbase + 16 + lane] = (float)eB;
        }
    }
}

// ---------------- Kernel 2: fused mask + expand-swap --------------------
// new[w,0]   = mask[w,0]   ? s[w,1]   : s[w,0]
// new[w,l>0] = mask[w,l-1] ? s[w,l-1] : s[w,l]
// Reads pmask[src] (8 B/vector, L2-hot) instead of states (268 MB) and
// re-expands bits to 0.0/1.0 floats (bit-exact: inputs are exactly 0/1).
// Acceptance test computed inline (same f64 formula as the old mask_kernel).
// Traffic: ~280 MB vs 536 MB for the load/store swap.
__global__ __launch_bounds__(256) void swap_kernel(
    const unsigned long long* __restrict__ pmask,
    const double* __restrict__ e64,
    const float* __restrict__ beta, const float* __restrict__ u,
    float* __restrict__ out)
{
    const long row0 = (long)blockIdx.x * 16;        // 16 rows/block, same (w,l)
    const int tid = threadIdx.x;
    const long row = row0 + (tid >> 4);             // (w*L + l)*K + k
    const int e = tid & 15;                         // float4 index in row
    const int w = (int)(row >> 15);
    const int l = (int)((row >> 9) & 63);
    const int k = (int)(row & 511);

    long src;
    if (l == 0) {
        const double db = (double)beta[1] - (double)beta[0];
        const double delta = (e64[row + PK] - e64[row]) * db;
        const float uv = u[(long)w * (PL - 1) * PK + k];
        src = row + (((double)uv < exp(delta)) ? PK : 0);
    } else {
        const double db = (double)beta[l] - (double)beta[l - 1];
        const double delta = (e64[row] - e64[row - PK]) * db;
        const float uv = u[((long)w * (PL - 1) + (l - 1)) * PK + k];
        src = row - (((double)uv < exp(delta)) ? PK : 0);
    }

    const unsigned long long pm = pmask[src];       // 16 lanes broadcast
    v4f f;                                          // element i=4e+c <-> bit c*16+e
    f.x = ((pm >> e)        & 1) ? 1.0f : 0.0f;
    f.y = ((pm >> (16 + e)) & 1) ? 1.0f : 0.0f;
    f.z = ((pm >> (32 + e)) & 1) ? 1.0f : 0.0f;
    f.w = ((pm >> (48 + e)) & 1) ? 1.0f : 0.0f;
    ((v4f*)(out + row * PN))[e] = f;                // block writes 16 KiB contig
}

extern "C" void kernel_launch(void* const* d_in, const int* in_sizes, int n_in,
                              void* d_out, int out_size, void* d_ws, size_t ws_size,
                              hipStream_t stream) {
    const float* states = (const float*)d_in[0];
    const float* Q      = (const float*)d_in[1];
    const float* beta   = (const float*)d_in[2];
    const float* u      = (const float*)d_in[3];

    float* e_out      = (float*)d_out;
    float* new_states = (float*)d_out + (long)PW * PL * PK;

    const long NV = (long)PW * PL * PK;
    double* e64 = (double*)d_ws;                                          // 8 MB
    unsigned long long* pmask = (unsigned long long*)((char*)d_ws + 8 * NV); // 8 MB

    // K1: 2048 blocks; block = 4 waves; wave = 4 iters x 32 vectors
    energies_kernel<<<2048, 256, 0, stream>>>(states, Q, e_out, e64, pmask);

    // K2: 1,048,576 rows / 16 per block = 65536 blocks
    swap_kernel<<<65536, 256, 0, stream>>>(pmask, e64, beta, u, new_states);
}

// Round 12
// 493.915 us; speedup vs baseline: 1.0654x; 1.0396x over previous
//
#include <hip/hip_runtime.h>
#include <math.h>

#define PW 32
#define PL 64
#define PK 512
#define PN 64
// vectors total: PW*PL*PK = 1,048,576

typedef int   v4i __attribute__((ext_vector_type(4)));
typedef float v4f __attribute__((ext_vector_type(4)));

// Permuted bit order everywhere: state element i = 4e + c  <->  bit p = c*16 + e.
// (4 per-component ballots over a float4 load give the packed mask directly;
// A-fragments use the same k-order so MFMA dot products are unchanged.)

// ---------------- Kernel 1: pack + energies (exact-int i8 MFMA) ----------
// R = llrint(Q * 2^28), 4 signed base-256 i8 digits; i32 MFMA exact; digits
// recombined in int64, scaled 2^-28 (e64 bit-identical to rounds 9-11).
// Round-12: A-fragment ds_reads hoisted OUT of the t-loop into 16 named
// v4i regs (t-invariant; kills the per-asm lgkmcnt(0) serialization);
// states loads staged into 8 named regs before any ballot consumes them;
// 8 iters/wave amortizes Afrag build.
constexpr int ITERS_PER_WAVE = 8;   // 32 vectors/iter -> 256 vectors/wave

#define DECLA(n) v4i A##n = Af[(n) * 64 + lane];

__global__ __launch_bounds__(256, 3) void energies_kernel(
    const float* __restrict__ states, const float* __restrict__ Q,
    float* __restrict__ e_out, double* __restrict__ e64,
    unsigned long long* __restrict__ pmask)
{
    __shared__ alignas(16) signed char Afrag[16 * 64 * 16];  // [k*4+jt][lane][b]

    const int tid  = threadIdx.x;
    const int lane = tid & 63;
    const int wv   = tid >> 6;
    const int w    = blockIdx.x >> 5;        // 32 blocks per w
    const int blk  = blockIdx.x & 31;

    // ---- build permuted digit fragments of Q[w] in LDS ----
    const float* Qw = Q + w * PN * PN;
    for (int e = tid; e < PN * PN; e += 256) {
        const int i = e >> 6, j = e & 63;
        long long R = llrint((double)Qw[e] * 268435456.0);   // * 2^28
        const int h = i & 3, b = i >> 2;                     // permuted k-pos
        const int frag_lane = (h << 4) | (j & 15);
        const int jt = j >> 4;
#pragma unroll
        for (int k = 0; k < 4; ++k) {
            const signed char d = (signed char)(R & 0xFF);
            R = (R - d) >> 8;
            Afrag[((k * 4 + jt) * 64 + frag_lane) * 16 + b] = d;
        }
    }
    __syncthreads();

    const v4i* Af = (const v4i*)Afrag;       // [(k*4+jt)*64 + lane]

    // ---- t-invariant A fragments: 16 named v4i (64 VGPRs) ----
    DECLA(0)  DECLA(1)  DECLA(2)  DECLA(3)
    DECLA(4)  DECLA(5)  DECLA(6)  DECLA(7)
    DECLA(8)  DECLA(9)  DECLA(10) DECLA(11)
    DECLA(12) DECLA(13) DECLA(14) DECLA(15)

    const long vw_base = (long)w * (PL * PK)
                       + (long)(blk * 4 + wv) * (32 * ITERS_PER_WAVE);
    const int h   = lane >> 4;
    const int g16 = (lane & 3) * 16;         // this lane's ballot slice
    const int itA = (lane & 15) >> 2;        // iter holding vector lane&15
    const int itO = (lane & 31) >> 2;        // iter holding vector lane&31

    for (int t = 0; t < ITERS_PER_WAVE; ++t) {
        const long vbase = vw_base + (long)t * 32;
        const float* sp = states + vbase * PN;

        // ---- stage all 8 coalesced 1-KiB loads before any ballot ----
        v4f f0 = ((const v4f*)(sp          ))[lane];
        v4f f1 = ((const v4f*)(sp +  4 * PN))[lane];
        v4f f2 = ((const v4f*)(sp +  8 * PN))[lane];
        v4f f3 = ((const v4f*)(sp + 12 * PN))[lane];
        v4f f4 = ((const v4f*)(sp + 16 * PN))[lane];
        v4f f5 = ((const v4f*)(sp + 20 * PN))[lane];
        v4f f6 = ((const v4f*)(sp + 24 * PN))[lane];
        v4f f7 = ((const v4f*)(sp + 28 * PN))[lane];

        unsigned long long pmA = 0, pmB = 0, pmO = 0;
#define PACK_IT(it, ff)                                                    \
        {                                                                  \
            const unsigned long long m0 = __ballot(ff.x != 0.0f);          \
            const unsigned long long m1 = __ballot(ff.y != 0.0f);          \
            const unsigned long long m2 = __ballot(ff.z != 0.0f);          \
            const unsigned long long m3 = __ballot(ff.w != 0.0f);          \
            const unsigned long long cand =                                \
                  ((m0 >> g16) & 0xFFFFull)                                \
                | (((m1 >> g16) & 0xFFFFull) << 16)                        \
                | (((m2 >> g16) & 0xFFFFull) << 32)                        \
                | (((m3 >> g16) & 0xFFFFull) << 48);                       \
            pmA = ((it) == itA)     ? cand : pmA;                          \
            pmB = ((it) == itA + 4) ? cand : pmB;                          \
            pmO = ((it) == itO)     ? cand : pmO;                          \
        }
        PACK_IT(0, f0) PACK_IT(1, f1) PACK_IT(2, f2) PACK_IT(3, f3)
        PACK_IT(4, f4) PACK_IT(5, f5) PACK_IT(6, f6) PACK_IT(7, f7)
#undef PACK_IT
        if (lane < 32) pmask[vbase + lane] = pmO;

        // ---- B fragments: byte b at group h = bit (h*16+b) of pm ----
        const unsigned int bA = (unsigned int)(pmA >> (h * 16)) & 0xFFFFu;
        const unsigned int bB = (unsigned int)(pmB >> (h * 16)) & 0xFFFFu;
        v4i BA, BB;
#pragma unroll
        for (int q = 0; q < 4; ++q) {
            BA[q] = (int)((((bA >> (4 * q)) & 0xFu) * 0x00204081u) & 0x01010101u);
            BB[q] = (int)((((bB >> (4 * q)) & 0xFu) * 0x00204081u) & 0x01010101u);
        }

        // ---- epilogue select bits: for row r, nibble over jt ----
        unsigned int xA[4], xB[4];
#pragma unroll
        for (int r = 0; r < 4; ++r) {
            xA[r] = (unsigned int)(pmA >> (r * 16 + h)) & 0x1111u;
            xB[r] = (unsigned int)(pmB >> (r * 16 + h)) & 0x1111u;
        }

        long long accA = 0, accB = 0;
#define DIGIT_K(k, a0, a1, a2, a3)                                          \
        {                                                                   \
            v4i CA0 = {0,0,0,0}, CA1 = {0,0,0,0}, CA2 = {0,0,0,0}, CA3 = {0,0,0,0}; \
            v4i CB0 = {0,0,0,0}, CB1 = {0,0,0,0}, CB2 = {0,0,0,0}, CB3 = {0,0,0,0}; \
            asm("s_nop 1\n\t"                                               \
                "v_mfma_i32_16x16x64_i8 %0, %8, %12, %0\n\t"                \
                "v_mfma_i32_16x16x64_i8 %4, %8, %13, %4\n\t"                \
                "v_mfma_i32_16x16x64_i8 %1, %9, %12, %1\n\t"                \
                "v_mfma_i32_16x16x64_i8 %5, %9, %13, %5\n\t"                \
                "v_mfma_i32_16x16x64_i8 %2, %10, %12, %2\n\t"               \
                "v_mfma_i32_16x16x64_i8 %6, %10, %13, %6\n\t"               \
                "v_mfma_i32_16x16x64_i8 %3, %11, %12, %3\n\t"               \
                "v_mfma_i32_16x16x64_i8 %7, %11, %13, %7\n\t"               \
                "s_nop 7\n\t"                                               \
                "s_nop 7"                                                   \
                : "+v"(CA0), "+v"(CA1), "+v"(CA2), "+v"(CA3),               \
                  "+v"(CB0), "+v"(CB1), "+v"(CB2), "+v"(CB3)                \
                : "v"(a0), "v"(a1), "v"(a2), "v"(a3), "v"(BA), "v"(BB));    \
            int akA = 0, akB = 0;                                           \
            _Pragma("unroll")                                               \
            for (int r = 0; r < 4; ++r) {                                   \
                akA += ((xA[r] >> 0)  & 1) * CA0[r];                        \
                akA += ((xA[r] >> 4)  & 1) * CA1[r];                        \
                akA += ((xA[r] >> 8)  & 1) * CA2[r];                        \
                akA += ((xA[r] >> 12) & 1) * CA3[r];                        \
                akB += ((xB[r] >> 0)  & 1) * CB0[r];                        \
                akB += ((xB[r] >> 4)  & 1) * CB1[r];                        \
                akB += ((xB[r] >> 8)  & 1) * CB2[r];                        \
                akB += ((xB[r] >> 12) & 1) * CB3[r];                        \
            }                                                               \
            accA += (long long)akA << (8 * (k));                            \
            accB += (long long)akB << (8 * (k));                            \
        }
        DIGIT_K(0, A0,  A1,  A2,  A3)
        DIGIT_K(1, A4,  A5,  A6,  A7)
        DIGIT_K(2, A8,  A9,  A10, A11)
        DIGIT_K(3, A12, A13, A14, A15)
#undef DIGIT_K

        // ---- reduce the 4 lane-groups holding the same v = lane&15 ----
        accA += __shfl_xor(accA, 16, 64);
        accA += __shfl_xor(accA, 32, 64);
        accB += __shfl_xor(accB, 16, 64);
        accB += __shfl_xor(accB, 32, 64);

        if (lane < 16) {
            const double eA = (double)accA * 0x1p-28;
            const double eB = (double)accB * 0x1p-28;
            e64[vbase + lane]        = eA;
            e_out[vbase + lane]      = (float)eA;
            e64[vbase + 16 + lane]   = eB;
            e_out[vbase + 16 + lane] = (float)eB;
        }
    }
}

// ---------------- Kernel 2: fused mask + expand-swap --------------------
// new[w,0]   = mask[w,0]   ? s[w,1]   : s[w,0]
// new[w,l>0] = mask[w,l-1] ? s[w,l-1] : s[w,l]
// Round-12: two-phase. Phase 1: ONE f64 exp per row (256 rows/block; round
// 11 computed it 16x redundantly per row), src offset into LDS. Phase 2: 16
// fully-coalesced expand-store iterations reading pmask[src] (L2-hot) and
// re-expanding bits to 0.0/1.0 floats (bit-exact: inputs are exactly 0/1).
__global__ __launch_bounds__(256) void swap_kernel(
    const unsigned long long* __restrict__ pmask,
    const double* __restrict__ e64,
    const float* __restrict__ beta, const float* __restrict__ u,
    float* __restrict__ out)
{
    __shared__ int srcl[256];
    const int tid = threadIdx.x;
    const long row0 = (long)blockIdx.x * 256;       // 256 rows, same (w,l)

    {   // ---- phase 1: acceptance per row ----
        const long row = row0 + tid;
        const int w = (int)(row >> 15);
        const int l = (int)((row >> 9) & 63);
        const int k = (int)(row & 511);
        long src;
        if (l == 0) {
            const double db = (double)beta[1] - (double)beta[0];
            const double delta = (e64[row + PK] - e64[row]) * db;
            const float uv = u[(long)w * (PL - 1) * PK + k];
            src = row + (((double)uv < exp(delta)) ? PK : 0);
        } else {
            const double db = (double)beta[l] - (double)beta[l - 1];
            const double delta = (e64[row] - e64[row - PK]) * db;
            const float uv = u[((long)w * (PL - 1) + (l - 1)) * PK + k];
            src = row - (((double)uv < exp(delta)) ? PK : 0);
        }
        srcl[tid] = (int)(src - row0);              // in [-512, 512)
    }
    __syncthreads();

    // ---- phase 2: expand 256 rows, coalesced 16-row groups ----
    const int e = tid & 15;
#pragma unroll
    for (int g = 0; g < 16; ++g) {
        const int r = g * 16 + (tid >> 4);
        const unsigned long long pm = pmask[row0 + srcl[r]];
        v4f f;                                      // elem i=4e+c <-> bit c*16+e
        f.x = ((pm >> e)        & 1) ? 1.0f : 0.0f;
        f.y = ((pm >> (16 + e)) & 1) ? 1.0f : 0.0f;
        f.z = ((pm >> (32 + e)) & 1) ? 1.0f : 0.0f;
        f.w = ((pm >> (48 + e)) & 1) ? 1.0f : 0.0f;
        ((v4f*)(out + (row0 + r) * PN))[e] = f;     // 4 KiB contiguous/group
    }
}

extern "C" void kernel_launch(void* const* d_in, const int* in_sizes, int n_in,
                              void* d_out, int out_size, void* d_ws, size_t ws_size,
                              hipStream_t stream) {
    const float* states = (const float*)d_in[0];
    const float* Q      = (const float*)d_in[1];
    const float* beta   = (const float*)d_in[2];
    const float* u      = (const float*)d_in[3];

    float* e_out      = (float*)d_out;
    float* new_states = (float*)d_out + (long)PW * PL * PK;

    const long NV = (long)PW * PL * PK;
    double* e64 = (double*)d_ws;                                          // 8 MB
    unsigned long long* pmask = (unsigned long long*)((char*)d_ws + 8 * NV); // 8 MB

    // K1: 1024 blocks; block = 4 waves; wave = 8 iters x 32 vectors
    //     -> 1024 * 4 * 256 = 1,048,576 vectors
    energies_kernel<<<1024, 256, 0, stream>>>(states, Q, e_out, e64, pmask);

    // K2: 1,048,576 rows / 256 per block = 4096 blocks
    swap_kernel<<<4096, 256, 0, stream>>>(pmask, e64, beta, u, new_states);
}

// Round 13
// 481.177 us; speedup vs baseline: 1.0936x; 1.0265x over previous
//
#include <hip/hip_runtime.h>
#include <math.h>

#define PW 32
#define PL 64
#define PK 512
#define PN 64
// vectors total: PW*PL*PK = 1,048,576

typedef int   v4i __attribute__((ext_vector_type(4)));
typedef float v4f __attribute__((ext_vector_type(4)));

// Permuted bit order everywhere: state element i = 4e + c  <->  bit p = c*16 + e.

// ---------------- Kernel 1: pack + energies (exact-int i8 MFMA) ----------
// R = llrint(Q * 2^28), 4 signed base-256 i8 digits; i32 MFMA exact; digits
// recombined in int64, scaled 2^-28 (e64 bit-identical to rounds 9-12).
// Round-13: __launch_bounds__(256,2) -> 256-VGPR budget; round-12's (256,3)
// capped at ~170 VGPR with a ~160+ live set (16 A-frags + 8 staged loads +
// 8 C tiles) -> suspected in-loop scratch spills. Also pmO cndmask chain
// removed (pmO == pmA for lanes<16, == pmB for lanes 16-31).
constexpr int ITERS_PER_WAVE = 8;   // 32 vectors/iter -> 256 vectors/wave

#define DECLA(n) v4i A##n = Af[(n) * 64 + lane];

__global__ __launch_bounds__(256, 2) void energies_kernel(
    const float* __restrict__ states, const float* __restrict__ Q,
    float* __restrict__ e_out, double* __restrict__ e64,
    unsigned long long* __restrict__ pmask)
{
    __shared__ alignas(16) signed char Afrag[16 * 64 * 16];  // [k*4+jt][lane][b]

    const int tid  = threadIdx.x;
    const int lane = tid & 63;
    const int wv   = tid >> 6;
    const int w    = blockIdx.x >> 5;        // 32 blocks per w
    const int blk  = blockIdx.x & 31;

    // ---- build permuted digit fragments of Q[w] in LDS ----
    const float* Qw = Q + w * PN * PN;
    for (int e = tid; e < PN * PN; e += 256) {
        const int i = e >> 6, j = e & 63;
        long long R = llrint((double)Qw[e] * 268435456.0);   // * 2^28
        const int h = i & 3, b = i >> 2;                     // permuted k-pos
        const int frag_lane = (h << 4) | (j & 15);
        const int jt = j >> 4;
#pragma unroll
        for (int k = 0; k < 4; ++k) {
            const signed char d = (signed char)(R & 0xFF);
            R = (R - d) >> 8;
            Afrag[((k * 4 + jt) * 64 + frag_lane) * 16 + b] = d;
        }
    }
    __syncthreads();

    const v4i* Af = (const v4i*)Afrag;       // [(k*4+jt)*64 + lane]

    // ---- t-invariant A fragments: 16 named v4i (64 VGPRs) ----
    DECLA(0)  DECLA(1)  DECLA(2)  DECLA(3)
    DECLA(4)  DECLA(5)  DECLA(6)  DECLA(7)
    DECLA(8)  DECLA(9)  DECLA(10) DECLA(11)
    DECLA(12) DECLA(13) DECLA(14) DECLA(15)

    const long vw_base = (long)w * (PL * PK)
                       + (long)(blk * 4 + wv) * (32 * ITERS_PER_WAVE);
    const int h   = lane >> 4;
    const int g16 = (lane & 3) * 16;         // this lane's ballot slice
    const int itA = (lane & 15) >> 2;        // iter holding vector lane&15

    for (int t = 0; t < ITERS_PER_WAVE; ++t) {
        const long vbase = vw_base + (long)t * 32;
        const float* sp = states + vbase * PN;

        // ---- stage all 8 coalesced 1-KiB loads before any ballot ----
        v4f f0 = ((const v4f*)(sp          ))[lane];
        v4f f1 = ((const v4f*)(sp +  4 * PN))[lane];
        v4f f2 = ((const v4f*)(sp +  8 * PN))[lane];
        v4f f3 = ((const v4f*)(sp + 12 * PN))[lane];
        v4f f4 = ((const v4f*)(sp + 16 * PN))[lane];
        v4f f5 = ((const v4f*)(sp + 20 * PN))[lane];
        v4f f6 = ((const v4f*)(sp + 24 * PN))[lane];
        v4f f7 = ((const v4f*)(sp + 28 * PN))[lane];

        unsigned long long pmA = 0, pmB = 0;
#define PACK_IT(it, ff)                                                    \
        {                                                                  \
            const unsigned long long m0 = __ballot(ff.x != 0.0f);          \
            const unsigned long long m1 = __ballot(ff.y != 0.0f);          \
            const unsigned long long m2 = __ballot(ff.z != 0.0f);          \
            const unsigned long long m3 = __ballot(ff.w != 0.0f);          \
            const unsigned long long cand =                                \
                  ((m0 >> g16) & 0xFFFFull)                                \
                | (((m1 >> g16) & 0xFFFFull) << 16)                        \
                | (((m2 >> g16) & 0xFFFFull) << 32)                        \
                | (((m3 >> g16) & 0xFFFFull) << 48);                       \
            pmA = ((it) == itA)     ? cand : pmA;                          \
            pmB = ((it) == itA + 4) ? cand : pmB;                          \
        }
        PACK_IT(0, f0) PACK_IT(1, f1) PACK_IT(2, f2) PACK_IT(3, f3)
        PACK_IT(4, f4) PACK_IT(5, f5) PACK_IT(6, f6) PACK_IT(7, f7)
#undef PACK_IT
        // lanes 0-15 own vectors vbase+lane (pmA); 16-31 own vbase+lane (pmB)
        if (lane < 32) pmask[vbase + lane] = (lane < 16) ? pmA : pmB;

        // ---- B fragments: byte b at group h = bit (h*16+b) of pm ----
        const unsigned int bA = (unsigned int)(pmA >> (h * 16)) & 0xFFFFu;
        const unsigned int bB = (unsigned int)(pmB >> (h * 16)) & 0xFFFFu;
        v4i BA, BB;
#pragma unroll
        for (int q = 0; q < 4; ++q) {
            BA[q] = (int)((((bA >> (4 * q)) & 0xFu) * 0x00204081u) & 0x01010101u);
            BB[q] = (int)((((bB >> (4 * q)) & 0xFu) * 0x00204081u) & 0x01010101u);
        }

        // ---- epilogue select bits: for row r, nibble over jt ----
        unsigned int xA[4], xB[4];
#pragma unroll
        for (int r = 0; r < 4; ++r) {
            xA[r] = (unsigned int)(pmA >> (r * 16 + h)) & 0x1111u;
            xB[r] = (unsigned int)(pmB >> (r * 16 + h)) & 0x1111u;
        }

        long long accA = 0, accB = 0;
#define DIGIT_K(k, a0, a1, a2, a3)                                          \
        {                                                                   \
            v4i CA0 = {0,0,0,0}, CA1 = {0,0,0,0}, CA2 = {0,0,0,0}, CA3 = {0,0,0,0}; \
            v4i CB0 = {0,0,0,0}, CB1 = {0,0,0,0}, CB2 = {0,0,0,0}, CB3 = {0,0,0,0}; \
            asm("s_nop 1\n\t"                                               \
                "v_mfma_i32_16x16x64_i8 %0, %8, %12, %0\n\t"                \
                "v_mfma_i32_16x16x64_i8 %4, %8, %13, %4\n\t"                \
                "v_mfma_i32_16x16x64_i8 %1, %9, %12, %1\n\t"                \
                "v_mfma_i32_16x16x64_i8 %5, %9, %13, %5\n\t"                \
                "v_mfma_i32_16x16x64_i8 %2, %10, %12, %2\n\t"               \
                "v_mfma_i32_16x16x64_i8 %6, %10, %13, %6\n\t"               \
                "v_mfma_i32_16x16x64_i8 %3, %11, %12, %3\n\t"               \
                "v_mfma_i32_16x16x64_i8 %7, %11, %13, %7\n\t"               \
                "s_nop 7\n\t"                                               \
                "s_nop 7"                                                   \
                : "+v"(CA0), "+v"(CA1), "+v"(CA2), "+v"(CA3),               \
                  "+v"(CB0), "+v"(CB1), "+v"(CB2), "+v"(CB3)                \
                : "v"(a0), "v"(a1), "v"(a2), "v"(a3), "v"(BA), "v"(BB));    \
            int akA = 0, akB = 0;                                           \
            _Pragma("unroll")                                               \
            for (int r = 0; r < 4; ++r) {                                   \
                akA += ((xA[r] >> 0)  & 1) * CA0[r];                        \
                akA += ((xA[r] >> 4)  & 1) * CA1[r];                        \
                akA += ((xA[r] >> 8)  & 1) * CA2[r];                        \
                akA += ((xA[r] >> 12) & 1) * CA3[r];                        \
                akB += ((xB[r] >> 0)  & 1) * CB0[r];                        \
                akB += ((xB[r] >> 4)  & 1) * CB1[r];                        \
                akB += ((xB[r] >> 8)  & 1) * CB2[r];                        \
                akB += ((xB[r] >> 12) & 1) * CB3[r];                        \
            }                                                               \
            accA += (long long)akA << (8 * (k));                            \
            accB += (long long)akB << (8 * (k));                            \
        }
        DIGIT_K(0, A0,  A1,  A2,  A3)
        DIGIT_K(1, A4,  A5,  A6,  A7)
        DIGIT_K(2, A8,  A9,  A10, A11)
        DIGIT_K(3, A12, A13, A14, A15)
#undef DIGIT_K

        // ---- reduce the 4 lane-groups holding the same v = lane&15 ----
        accA += __shfl_xor(accA, 16, 64);
        accA += __shfl_xor(accA, 32, 64);
        accB += __shfl_xor(accB, 16, 64);
        accB += __shfl_xor(accB, 32, 64);

        if (lane < 16) {
            const double eA = (double)accA * 0x1p-28;
            const double eB = (double)accB * 0x1p-28;
            e64[vbase + lane]        = eA;
            e_out[vbase + lane]      = (float)eA;
            e64[vbase + 16 + lane]   = eB;
            e_out[vbase + 16 + lane] = (float)eB;
        }
    }
}

// ---------------- Kernel 2: fused mask + expand-swap --------------------
// new[w,0]   = mask[w,0]   ? s[w,1]   : s[w,0]
// new[w,l>0] = mask[w,l-1] ? s[w,l-1] : s[w,l]
// Phase 1: one f64 exp per row (wave-amortized); src into LDS. Phase 2: 16
// coalesced expand-store iterations reading pmask[src] (L2-hot), bits ->
// 0.0/1.0 floats (bit-exact: inputs are exactly 0/1).
__global__ __launch_bounds__(256) void swap_kernel(
    const unsigned long long* __restrict__ pmask,
    const double* __restrict__ e64,
    const float* __restrict__ beta, const float* __restrict__ u,
    float* __restrict__ out)
{
    __shared__ int srcl[256];
    const int tid = threadIdx.x;
    const long row0 = (long)blockIdx.x * 256;       // 256 rows, same (w,l)

    {   // ---- phase 1: acceptance per row ----
        const long row = row0 + tid;
        const int w = (int)(row >> 15);
        const int l = (int)((row >> 9) & 63);
        const int k = (int)(row & 511);
        long src;
        if (l == 0) {
            const double db = (double)beta[1] - (double)beta[0];
            const double delta = (e64[row + PK] - e64[row]) * db;
            const float uv = u[(long)w * (PL - 1) * PK + k];
            src = row + (((double)uv < exp(delta)) ? PK : 0);
        } else {
            const double db = (double)beta[l] - (double)beta[l - 1];
            const double delta = (e64[row] - e64[row - PK]) * db;
            const float uv = u[((long)w * (PL - 1) + (l - 1)) * PK + k];
            src = row - (((double)uv < exp(delta)) ? PK : 0);
        }
        srcl[tid] = (int)(src - row0);              // in [-512, 512)
    }
    __syncthreads();

    // ---- phase 2: expand 256 rows, coalesced 16-row groups ----
    const int e = tid & 15;
#pragma unroll
    for (int g = 0; g < 16; ++g) {
        const int r = g * 16 + (tid >> 4);
        const unsigned long long pm = pmask[row0 + srcl[r]];
        v4f f;                                      // elem i=4e+c <-> bit c*16+e
        f.x = ((pm >> e)        & 1) ? 1.0f : 0.0f;
        f.y = ((pm >> (16 + e)) & 1) ? 1.0f : 0.0f;
        f.z = ((pm >> (32 + e)) & 1) ? 1.0f : 0.0f;
        f.w = ((pm >> (48 + e)) & 1) ? 1.0f : 0.0f;
        ((v4f*)(out + (row0 + r) * PN))[e] = f;     // 4 KiB contiguous/group
    }
}

extern "C" void kernel_launch(void* const* d_in, const int* in_sizes, int n_in,
                              void* d_out, int out_size, void* d_ws, size_t ws_size,
                              hipStream_t stream) {
    const float* states = (const float*)d_in[0];
    const float* Q      = (const float*)d_in[1];
    const float* beta   = (const float*)d_in[2];
    const float* u      = (const float*)d_in[3];

    float* e_out      = (float*)d_out;
    float* new_states = (float*)d_out + (long)PW * PL * PK;

    const long NV = (long)PW * PL * PK;
    double* e64 = (double*)d_ws;                                          // 8 MB
    unsigned long long* pmask = (unsigned long long*)((char*)d_ws + 8 * NV); // 8 MB

    // K1: 1024 blocks; block = 4 waves; wave = 8 iters x 32 vectors
    energies_kernel<<<1024, 256, 0, stream>>>(states, Q, e_out, e64, pmask);

    // K2: 1,048,576 rows / 256 per block = 4096 blocks
    swap_kernel<<<4096, 256, 0, stream>>>(pmask, e64, beta, u, new_states);
}